// Round 6
// baseline (372.042 us; speedup 1.0000x reference)
//
#include <hip/hip_runtime.h>

#define N_NODES 50000
#define N_EDGES 25000
#define NNZ     800000
#define DIM     256

#define CAP_E 88    // max nodes per edge (validated rounds 4-5, exact match)
#define CAP_V 56    // max edges per node

#define NBE 98      // coarse e-bins (e>>8)
#define NBV 196     // coarse v-bins (v>>8)
#define CE_COARSE 8800
#define CV_COARSE 4500
#define NNZ_PB 2048
#define P1_BLOCKS 391    // ceil(800000/2048)

// ws layout, BYTE offsets
#define B_A1   0            // 12,800,000 : bf16 A1 / S2; ALSO coarse pair bufs
#define B_CE   0            //  3,449,600 : u32 coarseE pairs (98 x 8800)
#define B_CV   3449600      //  3,528,000 : u32 coarseV pairs (196 x 4500)
#define B_CSRE 12800000     //  4,400,000 : u16 node-ids by edge (padded 88)
#define B_CSRV 17200000     //  5,600,000 : u16 edge-ids by node (padded 56)
#define B_WT   22800000     //    131,072 : W^T bf16 [n][k]
#define B_CURV 22931072     //    200,000 : u32 node degree
#define B_CURE 23131072     //    100,000 : u32 edge degree
#define B_S1B  23231072     //    100,000 : f32 sum d_v per edge
#define B_CCUR 23331072     //      1,176 : u32 coarse cursors
#define B_DV   23332248     //    200,000 : f32 rsqrt(deg_v)
// total ~23.6 MB (round-2 proved >=30.1 MB available)

typedef __attribute__((ext_vector_type(8))) short s8v;
typedef __attribute__((ext_vector_type(4))) float f4v;

__device__ __forceinline__ unsigned short f2bf(float f) {
    unsigned u = __float_as_uint(f);
    u = (u + 0x7FFFu + ((u >> 16) & 1u)) >> 16;   // RN-even
    return (unsigned short)u;
}
__device__ __forceinline__ float bf2f(unsigned short h) {
    return __uint_as_float(((unsigned)h) << 16);
}

// blocks [0,6250): X->bf16.  [6250,6282): W->WT bf16.  [6282,6673): coarse bin.
__global__ __launch_bounds__(256) void k_prep(
        const float* __restrict__ X, const float* __restrict__ W,
        const int* __restrict__ node_idx, const int* __restrict__ edge_idx,
        unsigned short* __restrict__ Xb, unsigned short* __restrict__ WTb,
        unsigned* __restrict__ ccurE, unsigned* __restrict__ ccurV,
        unsigned* __restrict__ coarseE, unsigned* __restrict__ coarseV) {
    if (blockIdx.x < 6250) {
        size_t i = ((size_t)blockIdx.x * 256 + threadIdx.x) * 8;
        float4 p0 = *(const float4*)(X + i);
        float4 p1 = *(const float4*)(X + i + 4);
        unsigned short o[8] = {f2bf(p0.x), f2bf(p0.y), f2bf(p0.z), f2bf(p0.w),
                               f2bf(p1.x), f2bf(p1.y), f2bf(p1.z), f2bf(p1.w)};
        *(s8v*)(Xb + i) = *(const s8v*)o;
        return;
    }
    if (blockIdx.x < 6282) {
        int t = (blockIdx.x - 6250) * 256 + threadIdx.x;
        int n = t >> 5;
        int k0 = (t & 31) * 8;
        unsigned short o[8];
#pragma unroll
        for (int j = 0; j < 8; ++j) o[j] = f2bf(W[(size_t)(k0 + j) * DIM + n]);
        *(s8v*)(WTb + (size_t)n * DIM + k0) = *(const s8v*)o;
        return;
    }

    __shared__ unsigned histE[NBE], histV[NBV], baseE[NBE], baseV[NBV];
    const int tid = threadIdx.x;
    const int pb  = blockIdx.x - 6282;
    const int base = pb * NNZ_PB;

    if (tid < NBE) histE[tid] = 0;
    if (tid < NBV) histV[tid] = 0;
    __syncthreads();

    int idx0 = base + tid * 4;
    int idx1 = base + 1024 + tid * 4;
    bool ok0 = idx0 < NNZ, ok1 = idx1 < NNZ;
    int4 v0 = ok0 ? *(const int4*)(node_idx + idx0) : (int4){0,0,0,0};
    int4 e0 = ok0 ? *(const int4*)(edge_idx + idx0) : (int4){0,0,0,0};
    int4 v1 = ok1 ? *(const int4*)(node_idx + idx1) : (int4){0,0,0,0};
    int4 e1 = ok1 ? *(const int4*)(edge_idx + idx1) : (int4){0,0,0,0};
    int vv[8] = {v0.x, v0.y, v0.z, v0.w, v1.x, v1.y, v1.z, v1.w};
    int ee[8] = {e0.x, e0.y, e0.z, e0.w, e1.x, e1.y, e1.z, e1.w};

    unsigned short locE[8], locV[8];
#pragma unroll
    for (int j = 0; j < 8; ++j) {
        bool ok = (j < 4) ? ok0 : ok1;
        if (ok) {
            locE[j] = (unsigned short)atomicAdd(&histE[ee[j] >> 8], 1u);
            locV[j] = (unsigned short)atomicAdd(&histV[vv[j] >> 8], 1u);
        }
    }
    __syncthreads();
    if (tid < NBE) baseE[tid] = atomicAdd(&ccurE[tid], histE[tid]);
    if (tid < NBV) baseV[tid] = atomicAdd(&ccurV[tid], histV[tid]);
    __syncthreads();

#pragma unroll
    for (int j = 0; j < 8; ++j) {
        bool ok = (j < 4) ? ok0 : ok1;
        if (ok) {
            unsigned e = (unsigned)ee[j], v = (unsigned)vv[j];
            unsigned pe = baseE[e >> 8] + locE[j];
            if (pe < CE_COARSE)
                coarseE[(size_t)(e >> 8) * CE_COARSE + pe] = ((e & 255u) << 16) | v;
            unsigned pv = baseV[v >> 8] + locV[j];
            if (pv < CV_COARSE)
                coarseV[(size_t)(v >> 8) * CV_COARSE + pv] = ((v & 255u) << 16) | e;
        }
    }
}

// pass 2: [0,98): coarseE -> csrE + cur_e; [98,294): coarseV -> csrV + cur_v + dv.
__global__ __launch_bounds__(256) void k_fine(
        const unsigned* __restrict__ coarseE, const unsigned* __restrict__ coarseV,
        const unsigned* __restrict__ ccurE, const unsigned* __restrict__ ccurV,
        unsigned short* __restrict__ csrE, unsigned short* __restrict__ csrV,
        unsigned* __restrict__ cur_e, unsigned* __restrict__ cur_v,
        float* __restrict__ dv) {
    __shared__ unsigned cnt[256];
    __shared__ unsigned short slots[256 * CAP_E];
    const int tid = threadIdx.x;
    cnt[tid] = 0;
    __syncthreads();

    if (blockIdx.x < NBE) {
        int b = blockIdx.x;
        unsigned n = ccurE[b]; n = n < CE_COARSE ? n : CE_COARSE;
        const unsigned* src = coarseE + (size_t)b * CE_COARSE;
        for (unsigned i = tid; i < n; i += 256) {
            unsigned p = src[i];
            unsigned f = p >> 16, v = p & 0xFFFFu;
            unsigned pos = atomicAdd(&cnt[f], 1u);
            if (pos < CAP_E) slots[f * CAP_E + pos] = (unsigned short)v;
        }
        __syncthreads();
        int e = b * 256 + tid;
        if (e < N_EDGES) cur_e[e] = cnt[tid];
        int rows = N_EDGES - b * 256; rows = rows < 256 ? rows : 256;
        unsigned words = (unsigned)rows * (CAP_E / 2);
        unsigned* dst = (unsigned*)(csrE + (size_t)b * 256 * CAP_E);
        const unsigned* s = (const unsigned*)slots;
        for (unsigned i = tid; i < words; i += 256) dst[i] = s[i];
    } else {
        int b = blockIdx.x - NBE;
        unsigned n = ccurV[b]; n = n < CV_COARSE ? n : CV_COARSE;
        const unsigned* src = coarseV + (size_t)b * CV_COARSE;
        for (unsigned i = tid; i < n; i += 256) {
            unsigned p = src[i];
            unsigned f = p >> 16, e = p & 0xFFFFu;
            unsigned pos = atomicAdd(&cnt[f], 1u);
            if (pos < CAP_V) slots[f * CAP_V + pos] = (unsigned short)e;
        }
        __syncthreads();
        int v = b * 256 + tid;
        if (v < N_NODES) {
            unsigned c = cnt[tid];
            cur_v[v] = c;
            dv[v] = c ? __frsqrt_rn((float)c) : 0.0f;
        }
        int rows = N_NODES - b * 256; rows = rows < 256 ? rows : 256;
        unsigned words = (unsigned)rows * (CAP_V / 2);
        unsigned* dst = (unsigned*)(csrV + (size_t)b * 256 * CAP_V);
        const unsigned* s = (const unsigned*)slots;
        for (unsigned i = tid; i < words; i += 256) dst[i] = s[i];
    }
}

// XCD-sliced edge gather: slice = blockIdx&7 -> 32 dims; per-XCD Xb slice is
// 3.2 MB (L2-resident). 16-lane group per edge; ushort2/lane = 64 B/member.
__global__ __launch_bounds__(256) void k_gather_edges(
        const unsigned short* __restrict__ Xb,
        const unsigned short* __restrict__ csrE,
        const unsigned* __restrict__ cur_e,
        const float* __restrict__ dv,
        unsigned short* __restrict__ A1, float* __restrict__ s1b) {
    const int slice = blockIdx.x & 7;
    const int chunk = blockIdx.x >> 3;
    const int g = threadIdx.x >> 4;
    const int l = threadIdx.x & 15;
    const int e = chunk * 16 + g;
    if (e >= N_EDGES) return;
    unsigned cnt = cur_e[e]; cnt = cnt < CAP_E ? cnt : CAP_E;
    const unsigned short* lst = csrE + (size_t)e * CAP_E;
    const unsigned dof = slice * 32 + l * 2;
    float a0 = 0.f, a1 = 0.f, ss = 0.f;
    unsigned j = 0;
    for (; j + 2 <= cnt; j += 2) {
        int v0 = lst[j], v1 = lst[j + 1];
        float s0 = dv[v0], s1 = dv[v1];
        ushort2 x0 = *(const ushort2*)(Xb + (size_t)v0 * DIM + dof);
        ushort2 x1 = *(const ushort2*)(Xb + (size_t)v1 * DIM + dof);
        a0 = fmaf(s0, bf2f(x0.x), a0); a1 = fmaf(s0, bf2f(x0.y), a1);
        a0 = fmaf(s1, bf2f(x1.x), a0); a1 = fmaf(s1, bf2f(x1.y), a1);
        ss += s0 + s1;
    }
    if (j < cnt) {
        int v = lst[j];
        float s = dv[v];
        ushort2 x = *(const ushort2*)(Xb + (size_t)v * DIM + dof);
        a0 = fmaf(s, bf2f(x.x), a0); a1 = fmaf(s, bf2f(x.y), a1);
        ss += s;
    }
    ushort2 o = {f2bf(a0), f2bf(a1)};
    *(ushort2*)(A1 + (size_t)e * DIM + dof) = o;
    if (slice == 0 && l == 0) s1b[e] = ss;
}

// LDS-free MFMA GEMM: S2 = (1/deg_e) * (A1 @ W + s1b*b), in place over A1.
__global__ __launch_bounds__(256) void k_gemm_mfma(
        const unsigned short* __restrict__ A,
        const unsigned short* __restrict__ WT,
        const float* __restrict__ bias,
        const unsigned* __restrict__ cur_e,
        const float* __restrict__ s1b,
        unsigned short* __restrict__ S2) {
    const int tid  = threadIdx.x;
    const int wv   = tid >> 6;
    const int lane = tid & 63;
    const int quad = lane >> 4;
    const int l16  = lane & 15;
    const int r0   = blockIdx.x * 64;
    const int nb   = wv * 64;

    f4v acc[4][4];
#pragma unroll
    for (int mt = 0; mt < 4; ++mt)
#pragma unroll
        for (int nt = 0; nt < 4; ++nt) acc[mt][nt] = (f4v){0.f, 0.f, 0.f, 0.f};

    for (int k0 = 0; k0 < DIM; k0 += 32) {
        s8v a[4], b[4];
#pragma unroll
        for (int nt = 0; nt < 4; ++nt) {
            int n = nb + nt * 16 + l16;
            b[nt] = *(const s8v*)(WT + (size_t)n * DIM + k0 + quad * 8);
        }
#pragma unroll
        for (int mt = 0; mt < 4; ++mt) {
            int m = r0 + mt * 16 + l16;
            m = (m < N_EDGES) ? m : (N_EDGES - 1);
            a[mt] = *(const s8v*)(A + (size_t)m * DIM + k0 + quad * 8);
        }
#pragma unroll
        for (int mt = 0; mt < 4; ++mt)
#pragma unroll
            for (int nt = 0; nt < 4; ++nt)
                acc[mt][nt] = __builtin_amdgcn_mfma_f32_16x16x32_bf16(
                    a[mt], b[nt], acc[mt][nt], 0, 0, 0);
    }

    __syncthreads();   // all in-place A reads drained before epilogue writes

    float bv[4];
#pragma unroll
    for (int nt = 0; nt < 4; ++nt) bv[nt] = bias[nb + nt * 16 + l16];

#pragma unroll
    for (int mt = 0; mt < 4; ++mt) {
#pragma unroll
        for (int reg = 0; reg < 4; ++reg) {
            int row = r0 + mt * 16 + quad * 4 + reg;
            if (row < N_EDGES) {
                unsigned ce = cur_e[row];
                float sc = ce ? 1.0f / (float)ce : 0.0f;
                float sb = s1b[row];
#pragma unroll
                for (int nt = 0; nt < 4; ++nt) {
                    float v = sc * (acc[mt][nt][reg] + sb * bv[nt]);
                    S2[(size_t)row * DIM + nb + nt * 16 + l16] = f2bf(v);
                }
            }
        }
    }
}

// XCD-sliced node gather: per-XCD S2 slice = 1.6 MB (L2-resident).
__global__ __launch_bounds__(256) void k_gather_nodes(
        const unsigned short* __restrict__ S2,
        const unsigned short* __restrict__ csrV,
        const unsigned* __restrict__ cur_v,
        const float* __restrict__ dv,
        float* __restrict__ out) {
    const int slice = blockIdx.x & 7;
    const int chunk = blockIdx.x >> 3;
    const int g = threadIdx.x >> 4;
    const int l = threadIdx.x & 15;
    const int v = chunk * 16 + g;
    if (v >= N_NODES) return;
    unsigned cnt = cur_v[v]; cnt = cnt < CAP_V ? cnt : CAP_V;
    const unsigned short* lst = csrV + (size_t)v * CAP_V;
    const unsigned dof = slice * 32 + l * 2;
    float a0 = 0.f, a1 = 0.f;
    unsigned j = 0;
    for (; j + 2 <= cnt; j += 2) {
        int e0 = lst[j], e1 = lst[j + 1];
        ushort2 x0 = *(const ushort2*)(S2 + (size_t)e0 * DIM + dof);
        ushort2 x1 = *(const ushort2*)(S2 + (size_t)e1 * DIM + dof);
        a0 += bf2f(x0.x) + bf2f(x1.x);
        a1 += bf2f(x0.y) + bf2f(x1.y);
    }
    if (j < cnt) {
        int e = lst[j];
        ushort2 x = *(const ushort2*)(S2 + (size_t)e * DIM + dof);
        a0 += bf2f(x.x); a1 += bf2f(x.y);
    }
    float s = dv[v];
    float2 o = {s * a0, s * a1};
    *(float2*)(out + (size_t)v * DIM + dof) = o;
}

extern "C" void kernel_launch(void* const* d_in, const int* in_sizes, int n_in,
                              void* d_out, int out_size, void* d_ws, size_t ws_size,
                              hipStream_t stream) {
    (void)in_sizes; (void)n_in; (void)out_size; (void)ws_size;
    const float* X        = (const float*)d_in[0];
    const int*   node_idx = (const int*)d_in[1];
    const int*   edge_idx = (const int*)d_in[2];
    const float* W        = (const float*)d_in[3];
    const float* bias     = (const float*)d_in[4];
    float* out = (float*)d_out;
    char*  ws  = (char*)d_ws;

    unsigned short* A1      = (unsigned short*)(ws + B_A1);
    unsigned*       coarseE = (unsigned*)(ws + B_CE);
    unsigned*       coarseV = (unsigned*)(ws + B_CV);
    unsigned short* csrE    = (unsigned short*)(ws + B_CSRE);
    unsigned short* csrV    = (unsigned short*)(ws + B_CSRV);
    unsigned short* WTb     = (unsigned short*)(ws + B_WT);
    unsigned*       cur_v   = (unsigned*)(ws + B_CURV);
    unsigned*       cur_e   = (unsigned*)(ws + B_CURE);
    float*          s1b     = (float*)(ws + B_S1B);
    unsigned*       ccurE   = (unsigned*)(ws + B_CCUR);
    unsigned*       ccurV   = ccurE + NBE;
    float*          dv      = (float*)(ws + B_DV);

    // Xb (bf16 X, 25.6 MB) lives in d_out — dead until k_gather_nodes
    // fully overwrites d_out at the end.
    unsigned short* Xb = (unsigned short*)d_out;

    hipMemsetAsync(ccurE, 0, (NBE + NBV) * sizeof(unsigned), stream);

    k_prep<<<6282 + P1_BLOCKS, 256, 0, stream>>>(X, W, node_idx, edge_idx,
                                                 Xb, WTb, ccurE, ccurV, coarseE, coarseV);
    k_fine<<<NBE + NBV, 256, 0, stream>>>(coarseE, coarseV, ccurE, ccurV,
                                          csrE, csrV, cur_e, cur_v, dv);
    k_gather_edges<<<((N_EDGES + 15) / 16) * 8, 256, 0, stream>>>(
        Xb, csrE, cur_e, dv, A1, s1b);
    k_gemm_mfma<<<(N_EDGES + 63) / 64, 256, 0, stream>>>(A1, WTb, bias, cur_e, s1b, A1);
    k_gather_nodes<<<((N_NODES + 15) / 16) * 8, 256, 0, stream>>>(
        A1, csrV, cur_v, dv, out);
}

// Round 7
// 271.616 us; speedup vs baseline: 1.3697x; 1.3697x over previous
//
#include <hip/hip_runtime.h>

#define N_NODES 50000
#define N_EDGES 25000
#define NNZ     800000
#define DIM     256

#define CAP_E 88    // max nodes per edge (validated rounds 4-6, exact match)
#define CAP_V 56    // max edges per node

#define NBE 98      // coarse e-bins (e>>8)
#define NBV 196     // coarse v-bins (v>>8)
#define CE_COARSE 8800
#define CV_COARSE 4500
#define NNZ_PB 2048
#define P1_BLOCKS 391    // ceil(800000/2048)

// ws layout, BYTE offsets
#define B_A1   0            // 12,800,000 : bf16 A1 / S2; ALSO coarse pair bufs
#define B_CE   0            //  3,449,600 : u32 coarseE pairs (98 x 8800)
#define B_CV   3449600      //  3,528,000 : u32 coarseV pairs (196 x 4500)
#define B_CSRE 12800000     //  4,400,000 : u16 node-ids by edge (padded 88)
#define B_CSRV 17200000     //  5,600,000 : u16 edge-ids by node (padded 56)
#define B_WT   22800000     //    131,072 : W^T bf16 [n][k]
#define B_CURV 22931072     //    200,000 : u32 node degree
#define B_CURE 23131072     //    100,000 : u32 edge degree
#define B_S1B  23231072     //    100,000 : f32 sum d_v per edge
#define B_CCUR 23331072     //      1,176 : u32 coarse cursors
#define B_DV   23332248     //    200,000 : f32 rsqrt(deg_v)
// total ~23.6 MB (round-2 proved >=30.1 MB available)

typedef __attribute__((ext_vector_type(8))) short s8v;
typedef __attribute__((ext_vector_type(4))) float f4v;

__device__ __forceinline__ unsigned short f2bf(float f) {
    unsigned u = __float_as_uint(f);
    u = (u + 0x7FFFu + ((u >> 16) & 1u)) >> 16;   // RN-even
    return (unsigned short)u;
}
__device__ __forceinline__ float bf2f(unsigned short h) {
    return __uint_as_float(((unsigned)h) << 16);
}

// blocks [0,6250): X->bf16.  [6250,6282): W->WT bf16.  [6282,6673): coarse bin.
__global__ __launch_bounds__(256) void k_prep(
        const float* __restrict__ X, const float* __restrict__ W,
        const int* __restrict__ node_idx, const int* __restrict__ edge_idx,
        unsigned short* __restrict__ Xb, unsigned short* __restrict__ WTb,
        unsigned* __restrict__ ccurE, unsigned* __restrict__ ccurV,
        unsigned* __restrict__ coarseE, unsigned* __restrict__ coarseV) {
    if (blockIdx.x < 6250) {
        size_t i = ((size_t)blockIdx.x * 256 + threadIdx.x) * 8;
        float4 p0 = *(const float4*)(X + i);
        float4 p1 = *(const float4*)(X + i + 4);
        unsigned short o[8] = {f2bf(p0.x), f2bf(p0.y), f2bf(p0.z), f2bf(p0.w),
                               f2bf(p1.x), f2bf(p1.y), f2bf(p1.z), f2bf(p1.w)};
        *(s8v*)(Xb + i) = *(const s8v*)o;
        return;
    }
    if (blockIdx.x < 6282) {
        int t = (blockIdx.x - 6250) * 256 + threadIdx.x;
        int n = t >> 5;
        int k0 = (t & 31) * 8;
        unsigned short o[8];
#pragma unroll
        for (int j = 0; j < 8; ++j) o[j] = f2bf(W[(size_t)(k0 + j) * DIM + n]);
        *(s8v*)(WTb + (size_t)n * DIM + k0) = *(const s8v*)o;
        return;
    }

    __shared__ unsigned histE[NBE], histV[NBV], baseE[NBE], baseV[NBV];
    const int tid = threadIdx.x;
    const int pb  = blockIdx.x - 6282;
    const int base = pb * NNZ_PB;

    if (tid < NBE) histE[tid] = 0;
    if (tid < NBV) histV[tid] = 0;
    __syncthreads();

    int idx0 = base + tid * 4;
    int idx1 = base + 1024 + tid * 4;
    bool ok0 = idx0 < NNZ, ok1 = idx1 < NNZ;
    int4 v0 = ok0 ? *(const int4*)(node_idx + idx0) : (int4){0,0,0,0};
    int4 e0 = ok0 ? *(const int4*)(edge_idx + idx0) : (int4){0,0,0,0};
    int4 v1 = ok1 ? *(const int4*)(node_idx + idx1) : (int4){0,0,0,0};
    int4 e1 = ok1 ? *(const int4*)(edge_idx + idx1) : (int4){0,0,0,0};
    int vv[8] = {v0.x, v0.y, v0.z, v0.w, v1.x, v1.y, v1.z, v1.w};
    int ee[8] = {e0.x, e0.y, e0.z, e0.w, e1.x, e1.y, e1.z, e1.w};

    unsigned short locE[8], locV[8];
#pragma unroll
    for (int j = 0; j < 8; ++j) {
        bool ok = (j < 4) ? ok0 : ok1;
        if (ok) {
            locE[j] = (unsigned short)atomicAdd(&histE[ee[j] >> 8], 1u);
            locV[j] = (unsigned short)atomicAdd(&histV[vv[j] >> 8], 1u);
        }
    }
    __syncthreads();
    if (tid < NBE) baseE[tid] = atomicAdd(&ccurE[tid], histE[tid]);
    if (tid < NBV) baseV[tid] = atomicAdd(&ccurV[tid], histV[tid]);
    __syncthreads();

#pragma unroll
    for (int j = 0; j < 8; ++j) {
        bool ok = (j < 4) ? ok0 : ok1;
        if (ok) {
            unsigned e = (unsigned)ee[j], v = (unsigned)vv[j];
            unsigned pe = baseE[e >> 8] + locE[j];
            if (pe < CE_COARSE)
                coarseE[(size_t)(e >> 8) * CE_COARSE + pe] = ((e & 255u) << 16) | v;
            unsigned pv = baseV[v >> 8] + locV[j];
            if (pv < CV_COARSE)
                coarseV[(size_t)(v >> 8) * CV_COARSE + pv] = ((v & 255u) << 16) | e;
        }
    }
}

// pass 2: [0,98): coarseE -> csrE + cur_e; [98,294): coarseV -> csrV + cur_v + dv.
__global__ __launch_bounds__(256) void k_fine(
        const unsigned* __restrict__ coarseE, const unsigned* __restrict__ coarseV,
        const unsigned* __restrict__ ccurE, const unsigned* __restrict__ ccurV,
        unsigned short* __restrict__ csrE, unsigned short* __restrict__ csrV,
        unsigned* __restrict__ cur_e, unsigned* __restrict__ cur_v,
        float* __restrict__ dv) {
    __shared__ unsigned cnt[256];
    __shared__ unsigned short slots[256 * CAP_E];
    const int tid = threadIdx.x;
    cnt[tid] = 0;
    __syncthreads();

    if (blockIdx.x < NBE) {
        int b = blockIdx.x;
        unsigned n = ccurE[b]; n = n < CE_COARSE ? n : CE_COARSE;
        const unsigned* src = coarseE + (size_t)b * CE_COARSE;
        for (unsigned i = tid; i < n; i += 256) {
            unsigned p = src[i];
            unsigned f = p >> 16, v = p & 0xFFFFu;
            unsigned pos = atomicAdd(&cnt[f], 1u);
            if (pos < CAP_E) slots[f * CAP_E + pos] = (unsigned short)v;
        }
        __syncthreads();
        int e = b * 256 + tid;
        if (e < N_EDGES) cur_e[e] = cnt[tid];
        int rows = N_EDGES - b * 256; rows = rows < 256 ? rows : 256;
        unsigned words = (unsigned)rows * (CAP_E / 2);
        unsigned* dst = (unsigned*)(csrE + (size_t)b * 256 * CAP_E);
        const unsigned* s = (const unsigned*)slots;
        for (unsigned i = tid; i < words; i += 256) dst[i] = s[i];
    } else {
        int b = blockIdx.x - NBE;
        unsigned n = ccurV[b]; n = n < CV_COARSE ? n : CV_COARSE;
        const unsigned* src = coarseV + (size_t)b * CV_COARSE;
        for (unsigned i = tid; i < n; i += 256) {
            unsigned p = src[i];
            unsigned f = p >> 16, e = p & 0xFFFFu;
            unsigned pos = atomicAdd(&cnt[f], 1u);
            if (pos < CAP_V) slots[f * CAP_V + pos] = (unsigned short)e;
        }
        __syncthreads();
        int v = b * 256 + tid;
        if (v < N_NODES) {
            unsigned c = cnt[tid];
            cur_v[v] = c;
            dv[v] = c ? __frsqrt_rn((float)c) : 0.0f;
        }
        int rows = N_NODES - b * 256; rows = rows < 256 ? rows : 256;
        unsigned words = (unsigned)rows * (CAP_V / 2);
        unsigned* dst = (unsigned*)(csrV + (size_t)b * 256 * CAP_V);
        const unsigned* s = (const unsigned*)slots;
        for (unsigned i = tid; i < words; i += 256) dst[i] = s[i];
    }
}

// one wave per edge, full 512 B row reads, unroll-4 for MLP:
// A1[e] = sum dv[v]*Xb[v]; s1b[e] = sum dv[v]
__global__ __launch_bounds__(256) void k_gather_edges(
        const unsigned short* __restrict__ Xb,
        const unsigned short* __restrict__ csrE,
        const unsigned* __restrict__ cur_e,
        const float* __restrict__ dv,
        unsigned short* __restrict__ A1, float* __restrict__ s1b) {
    int w = (blockIdx.x * 256 + threadIdx.x) >> 6;
    int lane = threadIdx.x & 63;
    if (w >= N_EDGES) return;
    unsigned cnt = cur_e[w]; cnt = cnt < CAP_E ? cnt : CAP_E;
    const unsigned short* lst = csrE + (size_t)w * CAP_E;
    float ax = 0.f, ay = 0.f, az = 0.f, aw = 0.f, ss = 0.f;
    unsigned j = 0;
    for (; j + 4 <= cnt; j += 4) {
        ushort4 ids = *(const ushort4*)(lst + j);   // wave-uniform, 8 B aligned
        int v0 = ids.x, v1 = ids.y, v2 = ids.z, v3 = ids.w;
        float s0 = dv[v0], s1 = dv[v1], s2 = dv[v2], s3 = dv[v3];
        ushort4 x0 = *(const ushort4*)(Xb + (size_t)v0 * DIM + lane * 4);
        ushort4 x1 = *(const ushort4*)(Xb + (size_t)v1 * DIM + lane * 4);
        ushort4 x2 = *(const ushort4*)(Xb + (size_t)v2 * DIM + lane * 4);
        ushort4 x3 = *(const ushort4*)(Xb + (size_t)v3 * DIM + lane * 4);
        ax = fmaf(s0, bf2f(x0.x), ax); ay = fmaf(s0, bf2f(x0.y), ay);
        az = fmaf(s0, bf2f(x0.z), az); aw = fmaf(s0, bf2f(x0.w), aw);
        ax = fmaf(s1, bf2f(x1.x), ax); ay = fmaf(s1, bf2f(x1.y), ay);
        az = fmaf(s1, bf2f(x1.z), az); aw = fmaf(s1, bf2f(x1.w), aw);
        ax = fmaf(s2, bf2f(x2.x), ax); ay = fmaf(s2, bf2f(x2.y), ay);
        az = fmaf(s2, bf2f(x2.z), az); aw = fmaf(s2, bf2f(x2.w), aw);
        ax = fmaf(s3, bf2f(x3.x), ax); ay = fmaf(s3, bf2f(x3.y), ay);
        az = fmaf(s3, bf2f(x3.z), az); aw = fmaf(s3, bf2f(x3.w), aw);
        ss += (s0 + s1) + (s2 + s3);
    }
    for (; j < cnt; ++j) {
        int v = lst[j];
        float s = dv[v];
        ushort4 x = *(const ushort4*)(Xb + (size_t)v * DIM + lane * 4);
        ax = fmaf(s, bf2f(x.x), ax); ay = fmaf(s, bf2f(x.y), ay);
        az = fmaf(s, bf2f(x.z), az); aw = fmaf(s, bf2f(x.w), aw);
        ss += s;
    }
    ushort4 o = {f2bf(ax), f2bf(ay), f2bf(az), f2bf(aw)};
    *(ushort4*)(A1 + (size_t)w * DIM + lane * 4) = o;
    if (lane == 0) s1b[w] = ss;
}

// LDS-free MFMA GEMM: S2 = (1/deg_e) * (A1 @ W + s1b*b), in place over A1.
__global__ __launch_bounds__(256) void k_gemm_mfma(
        const unsigned short* __restrict__ A,
        const unsigned short* __restrict__ WT,
        const float* __restrict__ bias,
        const unsigned* __restrict__ cur_e,
        const float* __restrict__ s1b,
        unsigned short* __restrict__ S2) {
    const int tid  = threadIdx.x;
    const int wv   = tid >> 6;
    const int lane = tid & 63;
    const int quad = lane >> 4;
    const int l16  = lane & 15;
    const int r0   = blockIdx.x * 64;
    const int nb   = wv * 64;

    f4v acc[4][4];
#pragma unroll
    for (int mt = 0; mt < 4; ++mt)
#pragma unroll
        for (int nt = 0; nt < 4; ++nt) acc[mt][nt] = (f4v){0.f, 0.f, 0.f, 0.f};

    for (int k0 = 0; k0 < DIM; k0 += 32) {
        s8v a[4], b[4];
#pragma unroll
        for (int nt = 0; nt < 4; ++nt) {
            int n = nb + nt * 16 + l16;
            b[nt] = *(const s8v*)(WT + (size_t)n * DIM + k0 + quad * 8);
        }
#pragma unroll
        for (int mt = 0; mt < 4; ++mt) {
            int m = r0 + mt * 16 + l16;
            m = (m < N_EDGES) ? m : (N_EDGES - 1);
            a[mt] = *(const s8v*)(A + (size_t)m * DIM + k0 + quad * 8);
        }
#pragma unroll
        for (int mt = 0; mt < 4; ++mt)
#pragma unroll
            for (int nt = 0; nt < 4; ++nt)
                acc[mt][nt] = __builtin_amdgcn_mfma_f32_16x16x32_bf16(
                    a[mt], b[nt], acc[mt][nt], 0, 0, 0);
    }

    __syncthreads();   // all in-place A reads drained before epilogue writes

    float bv[4];
#pragma unroll
    for (int nt = 0; nt < 4; ++nt) bv[nt] = bias[nb + nt * 16 + l16];

#pragma unroll
    for (int mt = 0; mt < 4; ++mt) {
#pragma unroll
        for (int reg = 0; reg < 4; ++reg) {
            int row = r0 + mt * 16 + quad * 4 + reg;
            if (row < N_EDGES) {
                unsigned ce = cur_e[row];
                float sc = ce ? 1.0f / (float)ce : 0.0f;
                float sb = s1b[row];
#pragma unroll
                for (int nt = 0; nt < 4; ++nt) {
                    float v = sc * (acc[mt][nt][reg] + sb * bv[nt]);
                    S2[(size_t)row * DIM + nb + nt * 16 + l16] = f2bf(v);
                }
            }
        }
    }
}

// one wave per node, full row reads, unroll-4: out[v] = dv[v] * sum S2[e]
__global__ __launch_bounds__(256) void k_gather_nodes(
        const unsigned short* __restrict__ S2,
        const unsigned short* __restrict__ csrV,
        const unsigned* __restrict__ cur_v,
        const float* __restrict__ dv,
        float* __restrict__ out) {
    int w = (blockIdx.x * 256 + threadIdx.x) >> 6;
    int lane = threadIdx.x & 63;
    if (w >= N_NODES) return;
    unsigned cnt = cur_v[w]; cnt = cnt < CAP_V ? cnt : CAP_V;
    const unsigned short* lst = csrV + (size_t)w * CAP_V;
    float ax = 0.f, ay = 0.f, az = 0.f, aw = 0.f;
    unsigned j = 0;
    for (; j + 4 <= cnt; j += 4) {
        ushort4 ids = *(const ushort4*)(lst + j);   // wave-uniform, 8 B aligned
        int e0 = ids.x, e1 = ids.y, e2 = ids.z, e3 = ids.w;
        ushort4 x0 = *(const ushort4*)(S2 + (size_t)e0 * DIM + lane * 4);
        ushort4 x1 = *(const ushort4*)(S2 + (size_t)e1 * DIM + lane * 4);
        ushort4 x2 = *(const ushort4*)(S2 + (size_t)e2 * DIM + lane * 4);
        ushort4 x3 = *(const ushort4*)(S2 + (size_t)e3 * DIM + lane * 4);
        ax += (bf2f(x0.x) + bf2f(x1.x)) + (bf2f(x2.x) + bf2f(x3.x));
        ay += (bf2f(x0.y) + bf2f(x1.y)) + (bf2f(x2.y) + bf2f(x3.y));
        az += (bf2f(x0.z) + bf2f(x1.z)) + (bf2f(x2.z) + bf2f(x3.z));
        aw += (bf2f(x0.w) + bf2f(x1.w)) + (bf2f(x2.w) + bf2f(x3.w));
    }
    for (; j < cnt; ++j) {
        int e = lst[j];
        ushort4 x = *(const ushort4*)(S2 + (size_t)e * DIM + lane * 4);
        ax += bf2f(x.x); ay += bf2f(x.y); az += bf2f(x.z); aw += bf2f(x.w);
    }
    float s = dv[w];
    float4 o = {s * ax, s * ay, s * az, s * aw};
    *(float4*)(out + (size_t)w * DIM + lane * 4) = o;
}

extern "C" void kernel_launch(void* const* d_in, const int* in_sizes, int n_in,
                              void* d_out, int out_size, void* d_ws, size_t ws_size,
                              hipStream_t stream) {
    (void)in_sizes; (void)n_in; (void)out_size; (void)ws_size;
    const float* X        = (const float*)d_in[0];
    const int*   node_idx = (const int*)d_in[1];
    const int*   edge_idx = (const int*)d_in[2];
    const float* W        = (const float*)d_in[3];
    const float* bias     = (const float*)d_in[4];
    float* out = (float*)d_out;
    char*  ws  = (char*)d_ws;

    unsigned short* A1      = (unsigned short*)(ws + B_A1);
    unsigned*       coarseE = (unsigned*)(ws + B_CE);
    unsigned*       coarseV = (unsigned*)(ws + B_CV);
    unsigned short* csrE    = (unsigned short*)(ws + B_CSRE);
    unsigned short* csrV    = (unsigned short*)(ws + B_CSRV);
    unsigned short* WTb     = (unsigned short*)(ws + B_WT);
    unsigned*       cur_v   = (unsigned*)(ws + B_CURV);
    unsigned*       cur_e   = (unsigned*)(ws + B_CURE);
    float*          s1b     = (float*)(ws + B_S1B);
    unsigned*       ccurE   = (unsigned*)(ws + B_CCUR);
    unsigned*       ccurV   = ccurE + NBE;
    float*          dv      = (float*)(ws + B_DV);

    // Xb (bf16 X, 25.6 MB) lives in d_out — dead until k_gather_nodes
    // fully overwrites d_out at the end.
    unsigned short* Xb = (unsigned short*)d_out;

    hipMemsetAsync(ccurE, 0, (NBE + NBV) * sizeof(unsigned), stream);

    k_prep<<<6282 + P1_BLOCKS, 256, 0, stream>>>(X, W, node_idx, edge_idx,
                                                 Xb, WTb, ccurE, ccurV, coarseE, coarseV);
    k_fine<<<NBE + NBV, 256, 0, stream>>>(coarseE, coarseV, ccurE, ccurV,
                                          csrE, csrV, cur_e, cur_v, dv);
    k_gather_edges<<<(N_EDGES * 64 + 255) / 256, 256, 0, stream>>>(
        Xb, csrE, cur_e, dv, A1, s1b);
    k_gemm_mfma<<<(N_EDGES + 63) / 64, 256, 0, stream>>>(A1, WTb, bias, cur_e, s1b, A1);
    k_gather_nodes<<<(N_NODES * 64 + 255) / 256, 256, 0, stream>>>(
        A1, csrV, cur_v, dv, out);
}